// Round 4
// baseline (380.560 us; speedup 1.0000x reference)
//
#include <hip/hip_runtime.h>

// Problem constants (from reference)
#define B_    256
#define CIN   48
#define CBOT  8
#define H_    4096
#define SCALE_ 0.35355339059327373f   // 1/sqrt(8)

// Single regular dispatch. Grid = (2 halves) x (256 batches) = 512 blocks of
// 512 threads -> 2 independent blocks per CU (launch_bounds caps VGPR at 128).
//
// Lessons baked in from rounds 1-3:
//   - multi-dispatch RAW pipelines race in this harness   -> ONE kernel
//   - cooperative launch / grid sync killed the container -> NO grid sync
//   - gram needs all H per batch                          -> each block reads
//     the WHOLE batch and computes the gram redundantly (identical FP order
//     in both sibling blocks -> bitwise-identical softmax), but keeps kqv
//     registers and writes output only for its own half of H.
// No device globals, no cross-block state: idempotent and replay-safe.
#define NT    512
#define HHALF 2048

__global__ __launch_bounds__(NT, 4) void ultimus_half(
    const float* __restrict__ x,        // [B, 48, 4096]
    const float* __restrict__ w_down,   // [8, 48]
    const float* __restrict__ w_up,     // [48, 8]
    float* __restrict__ out)            // [B, 48, 4096] (write-only)
{
    const int s = blockIdx.x;           // which half of H this block OWNS
    const int b = blockIdx.y;           // batch
    const int t = threadIdx.x;

    __shared__ float s_wdT[CIN * CBOT]; // w_down transposed: [c][o]
    __shared__ float s_red[8 * 36];     // per-wave gram partials (8 waves)
    __shared__ float s_am [CBOT * CBOT];// softmaxed attention matrix
    __shared__ float s_M  [CIN * CBOT]; // M = w_up @ am, [c][j]

    if (t < CIN * CBOT) {
        const int c = t >> 3, o = t & 7;
        s_wdT[t] = w_down[o * CIN + c];
    }
    __syncthreads();

    const float* xb = x + (size_t)b * (CIN * H_);
    const int hO = s * HHALF + (t << 2);         // own 4 columns (kept)
    const int hT = (1 - s) * HHALF + (t << 2);   // other half's 4 columns

    // ---- Phase 1: kqv for BOTH halves (own kept, other transient) ----
    float accO[CBOT][4], accT[CBOT][4];
    #pragma unroll
    for (int o = 0; o < CBOT; ++o) {
        accO[o][0] = accO[o][1] = accO[o][2] = accO[o][3] = 0.0f;
        accT[o][0] = accT[o][1] = accT[o][2] = accT[o][3] = 0.0f;
    }

    #pragma unroll 4
    for (int c = 0; c < CIN; ++c) {
        const float4 xvO = *reinterpret_cast<const float4*>(xb + (size_t)c * H_ + hO);
        const float4 xvT = *reinterpret_cast<const float4*>(xb + (size_t)c * H_ + hT);
        #pragma unroll
        for (int o = 0; o < CBOT; ++o) {
            const float w = s_wdT[c * CBOT + o];
            accO[o][0] += w * xvO.x;  accO[o][1] += w * xvO.y;
            accO[o][2] += w * xvO.z;  accO[o][3] += w * xvO.w;
            accT[o][0] += w * xvT.x;  accT[o][1] += w * xvT.y;
            accT[o][2] += w * xvT.z;  accT[o][3] += w * xvT.w;
        }
    }

    // ---- Phase 2: FULL gram (own + other half), 36 upper-tri values ----
    float g[36];
    {
        int idx = 0;
        #pragma unroll
        for (int i = 0; i < CBOT; ++i) {
            #pragma unroll
            for (int j = i; j < CBOT; ++j, ++idx) {
                g[idx] = accO[i][0] * accO[j][0] + accO[i][1] * accO[j][1]
                       + accO[i][2] * accO[j][2] + accO[i][3] * accO[j][3]
                       + accT[i][0] * accT[j][0] + accT[i][1] * accT[j][1]
                       + accT[i][2] * accT[j][2] + accT[i][3] * accT[j][3];
            }
        }
    }
    #pragma unroll
    for (int k = 0; k < 36; ++k) {
        float v = g[k];
        v += __shfl_down(v, 32, 64);
        v += __shfl_down(v, 16, 64);
        v += __shfl_down(v,  8, 64);
        v += __shfl_down(v,  4, 64);
        v += __shfl_down(v,  2, 64);
        v += __shfl_down(v,  1, 64);
        g[k] = v;   // lane 0 holds wave sum
    }
    const int wave = t >> 6;   // 8 waves
    const int lane = t & 63;
    if (lane == 0) {
        #pragma unroll
        for (int k = 0; k < 36; ++k) s_red[wave * 36 + k] = g[k];
    }
    __syncthreads();
    if (t < 36) {
        float v = 0.0f;
        #pragma unroll
        for (int w = 0; w < 8; ++w) v += s_red[w * 36 + t];
        s_red[t] = v;   // column t: writes own index, others never read it
    }
    __syncthreads();

    // ---- Phase 3: softmax rows (threads 0..7) ----
    if (t < 8) {
        float row[8];
        #pragma unroll
        for (int j = 0; j < 8; ++j) {
            const int i2 = t < j ? t : j;
            const int j2 = t < j ? j : t;
            const int tri = i2 * 8 - (i2 * (i2 - 1)) / 2 + (j2 - i2);
            row[j] = s_red[tri] * SCALE_;
        }
        float m = row[0];
        #pragma unroll
        for (int j = 1; j < 8; ++j) m = fmaxf(m, row[j]);
        float sum = 0.0f;
        #pragma unroll
        for (int j = 0; j < 8; ++j) { row[j] = __expf(row[j] - m); sum += row[j]; }
        const float inv = 1.0f / sum;
        #pragma unroll
        for (int j = 0; j < 8; ++j) s_am[t * 8 + j] = row[j] * inv;
    }
    __syncthreads();

    // M[c][j] = sum_o w_up[c][o] * am[o][j]  (folds both tiny matmuls)
    if (t < CIN * CBOT) {
        const int c = t >> 3, j = t & 7;
        float v = 0.0f;
        #pragma unroll
        for (int o = 0; o < CBOT; ++o)
            v += w_up[c * CBOT + o] * s_am[o * CBOT + j];
        s_M[t] = v;
    }
    __syncthreads();

    // ---- Phase 4: out[c][hO] = sum_j M[c][j] * kqv[j][hO] (registers) ----
    float* ob = out + (size_t)b * (CIN * H_) + hO;
    #pragma unroll 8
    for (int c = 0; c < CIN; ++c) {
        float4 r;
        r.x = r.y = r.z = r.w = 0.0f;
        #pragma unroll
        for (int j = 0; j < CBOT; ++j) {
            const float mcj = s_M[c * CBOT + j];
            r.x += mcj * accO[j][0];
            r.y += mcj * accO[j][1];
            r.z += mcj * accO[j][2];
            r.w += mcj * accO[j][3];
        }
        *reinterpret_cast<float4*>(ob + (size_t)c * H_) = r;
    }
}

extern "C" void kernel_launch(void* const* d_in, const int* in_sizes, int n_in,
                              void* d_out, int out_size, void* d_ws, size_t ws_size,
                              hipStream_t stream) {
    const float* x      = (const float*)d_in[0];
    const float* w_down = (const float*)d_in[1];
    const float* w_up   = (const float*)d_in[2];
    float* out          = (float*)d_out;

    hipLaunchKernelGGL(ultimus_half, dim3(2, B_), dim3(NT), 0, stream,
                       x, w_down, w_up, out);
}

// Round 6
// 344.321 us; speedup vs baseline: 1.1052x; 1.1052x over previous
//
#include <hip/hip_runtime.h>

// Problem constants (from reference)
#define B_    256
#define CIN   48
#define CBOT  8
#define H_    4096
#define SCALE_ 0.35355339059327373f   // 1/sqrt(8)

// Round-0 structure (minimal traffic: x read once, out written once, one
// 1024-thread block per batch, kqv column-local in registers) + a DEEP
// EXPLICIT LOAD PIPELINE. Rounds 0/4 showed the kernel is memory-latency
// bound (~2.6 TB/s at ~6-8 outstanding loads/wave); this round holds the
// structure fixed and raises ILP: a 12-deep float4 ring buffer, fully
// unrolled so all indices are compile-time constants (no scratch).
// Output stores are non-temporal (native ext_vector type -- HIP's float4
// class is rejected by __builtin_nontemporal_store).
#define NBUF  12

typedef float vfloat4 __attribute__((ext_vector_type(4)));

__global__ __launch_bounds__(1024, 4) void ultimus_kernel(
    const float* __restrict__ x,        // [B, 48, 4096]
    const float* __restrict__ w_down,   // [8, 48]
    const float* __restrict__ w_up,     // [48, 8]
    float* __restrict__ out)            // [B, 48, 4096]
{
    const int b = blockIdx.x;
    const int t = threadIdx.x;

    __shared__ float s_wdT[CIN * CBOT];   // w_down transposed: [c][o]
    __shared__ float s_wu [CIN * CBOT];   // w_up as given (row-major [48,8])
    __shared__ float s_red[16 * 36];      // per-wave gram partials
    __shared__ float s_am [CBOT * CBOT];  // softmaxed attention matrix

    if (t < CIN * CBOT) {
        const int c = t >> 3, o = t & 7;
        s_wdT[t] = w_down[o * CIN + c];
        s_wu[t]  = w_up[t];
    }
    __syncthreads();

    const int h0 = t << 2;
    const float* xb = x + (size_t)b * (CIN * H_) + h0;

    // ---- Phase 1: kqv[o][0..3] = sum_c w_down[o][c] * x[b][c][h0..h0+3] ----
    // 12-deep software pipeline: 12 independent float4 loads in flight per
    // lane at all times. Fully unrolled -> buf indices are static.
    vfloat4 buf[NBUF];
    #pragma unroll
    for (int i = 0; i < NBUF; ++i)
        buf[i] = *reinterpret_cast<const vfloat4*>(xb + (size_t)i * H_);

    float acc[CBOT][4];
    #pragma unroll
    for (int o = 0; o < CBOT; ++o)
        acc[o][0] = acc[o][1] = acc[o][2] = acc[o][3] = 0.0f;

    #pragma unroll
    for (int c = 0; c < CIN; ++c) {
        const vfloat4 xv = buf[c % NBUF];
        if (c + NBUF < CIN)
            buf[c % NBUF] =
                *reinterpret_cast<const vfloat4*>(xb + (size_t)(c + NBUF) * H_);
        #pragma unroll
        for (int o = 0; o < CBOT; ++o) {
            const float w = s_wdT[c * CBOT + o];
            acc[o][0] += w * xv.x;
            acc[o][1] += w * xv.y;
            acc[o][2] += w * xv.z;
            acc[o][3] += w * xv.w;
        }
    }

    // ---- Phase 2: gram G[i][j] (upper triangle, 36 values), block-reduced ----
    float g[36];
    {
        int idx = 0;
        #pragma unroll
        for (int i = 0; i < CBOT; ++i) {
            #pragma unroll
            for (int j = i; j < CBOT; ++j, ++idx) {
                g[idx] = acc[i][0] * acc[j][0] + acc[i][1] * acc[j][1]
                       + acc[i][2] * acc[j][2] + acc[i][3] * acc[j][3];
            }
        }
    }
    #pragma unroll
    for (int k = 0; k < 36; ++k) {
        float v = g[k];
        v += __shfl_down(v, 32, 64);
        v += __shfl_down(v, 16, 64);
        v += __shfl_down(v,  8, 64);
        v += __shfl_down(v,  4, 64);
        v += __shfl_down(v,  2, 64);
        v += __shfl_down(v,  1, 64);
        g[k] = v;   // lane 0 holds wave sum
    }
    const int wave = t >> 6;
    const int lane = t & 63;
    if (lane == 0) {
        #pragma unroll
        for (int k = 0; k < 36; ++k) s_red[wave * 36 + k] = g[k];
    }
    __syncthreads();

    // cross-wave reduce: lanes 0..35 of wave 0
    if (t < 36) {
        float v = 0.0f;
        #pragma unroll
        for (int w = 0; w < 16; ++w) v += s_red[w * 36 + t];
        s_red[t] = v;
    }
    __syncthreads();

    // ---- Phase 3: softmax rows (threads 0..7) ----
    if (t < 8) {
        float row[8];
        #pragma unroll
        for (int j = 0; j < 8; ++j) {
            const int i2 = t < j ? t : j;
            const int j2 = t < j ? j : t;
            const int tri = i2 * 8 - (i2 * (i2 - 1)) / 2 + (j2 - i2);
            row[j] = s_red[tri] * SCALE_;
        }
        float m = row[0];
        #pragma unroll
        for (int j = 1; j < 8; ++j) m = fmaxf(m, row[j]);
        float s = 0.0f;
        #pragma unroll
        for (int j = 0; j < 8; ++j) { row[j] = __expf(row[j] - m); s += row[j]; }
        const float inv = 1.0f / s;
        #pragma unroll
        for (int j = 0; j < 8; ++j) s_am[t * 8 + j] = row[j] * inv;
    }
    __syncthreads();

    // ---- Phase 4: z = am @ kqv (registers), out = w_up @ z ----
    float z[CBOT][4];
    #pragma unroll
    for (int o = 0; o < CBOT; ++o) {
        float a0 = 0.f, a1 = 0.f, a2 = 0.f, a3 = 0.f;
        #pragma unroll
        for (int j = 0; j < CBOT; ++j) {
            const float a = s_am[o * 8 + j];
            a0 += a * acc[j][0];
            a1 += a * acc[j][1];
            a2 += a * acc[j][2];
            a3 += a * acc[j][3];
        }
        z[o][0] = a0; z[o][1] = a1; z[o][2] = a2; z[o][3] = a3;
    }

    float* ob = out + (size_t)b * (CIN * H_) + h0;
    #pragma unroll 8
    for (int c = 0; c < CIN; ++c) {
        vfloat4 r;
        r.x = r.y = r.z = r.w = 0.0f;
        #pragma unroll
        for (int o = 0; o < CBOT; ++o) {
            const float w = s_wu[c * CBOT + o];
            r.x += w * z[o][0];
            r.y += w * z[o][1];
            r.z += w * z[o][2];
            r.w += w * z[o][3];
        }
        __builtin_nontemporal_store(r, reinterpret_cast<vfloat4*>(ob + (size_t)c * H_));
    }
}

extern "C" void kernel_launch(void* const* d_in, const int* in_sizes, int n_in,
                              void* d_out, int out_size, void* d_ws, size_t ws_size,
                              hipStream_t stream) {
    const float* x      = (const float*)d_in[0];
    const float* w_down = (const float*)d_in[1];
    const float* w_up   = (const float*)d_in[2];
    float* out          = (float*)d_out;

    hipLaunchKernelGGL(ultimus_kernel, dim3(B_), dim3(1024), 0, stream,
                       x, w_down, w_up, out);
}

// Round 7
// 340.703 us; speedup vs baseline: 1.1170x; 1.0106x over previous
//
#include <hip/hip_runtime.h>

// Problem constants (from reference)
#define B_    256
#define CIN   48
#define CBOT  8
#define H_    4096
#define SCALE_ 0.35355339059327373f   // 1/sqrt(8)

// Round-6 structure (minimal traffic, NT stores, one 1024-thread block per
// batch) + an ENFORCED load pipeline. Round 6 proved the compiler collapsed
// the source-level ring buffer (VGPR stayed 64): plain loads get sunk to
// just-before-use. This round pins the pipeline with asm volatile
// global_load_dwordx4 (volatile order = issue order) and counted
// s_waitcnt vmcnt(N), each wait tied to its buffer register via "+v" so the
// consuming FMAs data-depend on the wait (no global sched fences needed).
// Depth 8 -> 8 KB in flight per wave, 16 waves/CU => ~128 KB/CU >> the
// ~22 KB/CU Little's-law requirement at 6.3 TB/s.
#define NBUF  8

typedef float vf4 __attribute__((ext_vector_type(4)));

__device__ __forceinline__ void vmwait(int n, vf4& v) {
    // n is compile-time constant after full unroll -> switch folds away.
    switch (n) {
        case 0: asm volatile("s_waitcnt vmcnt(0)" : "+v"(v)); break;
        case 1: asm volatile("s_waitcnt vmcnt(1)" : "+v"(v)); break;
        case 2: asm volatile("s_waitcnt vmcnt(2)" : "+v"(v)); break;
        case 3: asm volatile("s_waitcnt vmcnt(3)" : "+v"(v)); break;
        case 4: asm volatile("s_waitcnt vmcnt(4)" : "+v"(v)); break;
        case 5: asm volatile("s_waitcnt vmcnt(5)" : "+v"(v)); break;
        case 6: asm volatile("s_waitcnt vmcnt(6)" : "+v"(v)); break;
        default: asm volatile("s_waitcnt vmcnt(7)" : "+v"(v)); break;
    }
}

__global__ __launch_bounds__(1024, 4) void ultimus_kernel(
    const float* __restrict__ x,        // [B, 48, 4096]
    const float* __restrict__ w_down,   // [8, 48]
    const float* __restrict__ w_up,     // [48, 8]
    float* __restrict__ out)            // [B, 48, 4096]
{
    const int b = blockIdx.x;
    const int t = threadIdx.x;

    __shared__ float s_wdT[CIN * CBOT];   // w_down transposed: [c][o]
    __shared__ float s_wu [CIN * CBOT];   // w_up as given (row-major [48,8])
    __shared__ float s_red[16 * 36];      // per-wave gram partials
    __shared__ float s_am [CBOT * CBOT];  // softmaxed attention matrix

    if (t < CIN * CBOT) {
        const int c = t >> 3, o = t & 7;
        s_wdT[t] = w_down[o * CIN + c];
        s_wu[t]  = w_up[t];
    }
    __syncthreads();

    const int h0 = t << 2;
    const float* xb = x + (size_t)b * (CIN * H_) + h0;

    // ---- Phase 1: enforced 8-deep load pipeline ----
    vf4 buf[NBUF];
    #pragma unroll
    for (int i = 0; i < NBUF; ++i) {
        const float* p = xb + (size_t)i * H_;
        asm volatile("global_load_dwordx4 %0, %1, off" : "=v"(buf[i]) : "v"(p));
    }

    float acc[CBOT][4];
    #pragma unroll
    for (int o = 0; o < CBOT; ++o)
        acc[o][0] = acc[o][1] = acc[o][2] = acc[o][3] = 0.0f;

    #pragma unroll
    for (int c = 0; c < CIN; ++c) {
        const int wcnt = (47 - c) < (NBUF - 1) ? (47 - c) : (NBUF - 1);
        vmwait(wcnt, buf[c & (NBUF - 1)]);
        const vf4 xv = buf[c & (NBUF - 1)];
        if (c + NBUF < CIN) {
            const float* p = xb + (size_t)(c + NBUF) * H_;
            asm volatile("global_load_dwordx4 %0, %1, off"
                         : "=v"(buf[c & (NBUF - 1)]) : "v"(p));
        }
        #pragma unroll
        for (int o = 0; o < CBOT; ++o) {
            const float w = s_wdT[c * CBOT + o];
            acc[o][0] += w * xv.x;
            acc[o][1] += w * xv.y;
            acc[o][2] += w * xv.z;
            acc[o][3] += w * xv.w;
        }
    }

    // ---- Phase 2: gram G[i][j] (upper triangle, 36 values), block-reduced ----
    float g[36];
    {
        int idx = 0;
        #pragma unroll
        for (int i = 0; i < CBOT; ++i) {
            #pragma unroll
            for (int j = i; j < CBOT; ++j, ++idx) {
                g[idx] = acc[i][0] * acc[j][0] + acc[i][1] * acc[j][1]
                       + acc[i][2] * acc[j][2] + acc[i][3] * acc[j][3];
            }
        }
    }
    #pragma unroll
    for (int k = 0; k < 36; ++k) {
        float v = g[k];
        v += __shfl_down(v, 32, 64);
        v += __shfl_down(v, 16, 64);
        v += __shfl_down(v,  8, 64);
        v += __shfl_down(v,  4, 64);
        v += __shfl_down(v,  2, 64);
        v += __shfl_down(v,  1, 64);
        g[k] = v;   // lane 0 holds wave sum
    }
    const int wave = t >> 6;
    const int lane = t & 63;
    if (lane == 0) {
        #pragma unroll
        for (int k = 0; k < 36; ++k) s_red[wave * 36 + k] = g[k];
    }
    __syncthreads();

    // cross-wave reduce: lanes 0..35 of wave 0
    if (t < 36) {
        float v = 0.0f;
        #pragma unroll
        for (int w = 0; w < 16; ++w) v += s_red[w * 36 + t];
        s_red[t] = v;
    }
    __syncthreads();

    // ---- Phase 3: softmax rows (threads 0..7) ----
    if (t < 8) {
        float row[8];
        #pragma unroll
        for (int j = 0; j < 8; ++j) {
            const int i2 = t < j ? t : j;
            const int j2 = t < j ? j : t;
            const int tri = i2 * 8 - (i2 * (i2 - 1)) / 2 + (j2 - i2);
            row[j] = s_red[tri] * SCALE_;
        }
        float m = row[0];
        #pragma unroll
        for (int j = 1; j < 8; ++j) m = fmaxf(m, row[j]);
        float s = 0.0f;
        #pragma unroll
        for (int j = 0; j < 8; ++j) { row[j] = __expf(row[j] - m); s += row[j]; }
        const float inv = 1.0f / s;
        #pragma unroll
        for (int j = 0; j < 8; ++j) s_am[t * 8 + j] = row[j] * inv;
    }
    __syncthreads();

    // ---- Phase 4: z = am @ kqv (registers), out = w_up @ z ----
    float z[CBOT][4];
    #pragma unroll
    for (int o = 0; o < CBOT; ++o) {
        float a0 = 0.f, a1 = 0.f, a2 = 0.f, a3 = 0.f;
        #pragma unroll
        for (int j = 0; j < CBOT; ++j) {
            const float a = s_am[o * 8 + j];
            a0 += a * acc[j][0];
            a1 += a * acc[j][1];
            a2 += a * acc[j][2];
            a3 += a * acc[j][3];
        }
        z[o][0] = a0; z[o][1] = a1; z[o][2] = a2; z[o][3] = a3;
    }

    float* ob = out + (size_t)b * (CIN * H_) + h0;
    #pragma unroll 8
    for (int c = 0; c < CIN; ++c) {
        vf4 r;
        r.x = r.y = r.z = r.w = 0.0f;
        #pragma unroll
        for (int o = 0; o < CBOT; ++o) {
            const float w = s_wu[c * CBOT + o];
            r.x += w * z[o][0];
            r.y += w * z[o][1];
            r.z += w * z[o][2];
            r.w += w * z[o][3];
        }
        __builtin_nontemporal_store(r, reinterpret_cast<vf4*>(ob + (size_t)c * H_));
    }
}

extern "C" void kernel_launch(void* const* d_in, const int* in_sizes, int n_in,
                              void* d_out, int out_size, void* d_ws, size_t ws_size,
                              hipStream_t stream) {
    const float* x      = (const float*)d_in[0];
    const float* w_down = (const float*)d_in[1];
    const float* w_up   = (const float*)d_in[2];
    float* out          = (float*)d_out;

    hipLaunchKernelGGL(ultimus_kernel, dim3(B_), dim3(1024), 0, stream,
                       x, w_down, w_up, out);
}